// Round 8
// baseline (635.984 us; speedup 1.0000x reference)
//
#include <hip/hip_runtime.h>
#include <hip/hip_fp16.h>

#define DF 64
#define MSG 20
#define HID2 10
#define NODES 50000
#define EDGES 800000
#define GRAPHS 512
#define RSTRIDE 32   // halves per padded output row = 64 B (one cache line)
#define NB1 ((NODES + 255) / 256)   // 196

// edge-stage tiling
#define EB_THREADS 256
#define EB_TILE    512               // edges per block
#define EB_EPT     2                 // edges per thread
#define NPH        4                 // K phases (16 floats each)
#define XW_STRIDE  9                 // LDS words per edge per phase (8 data + 1 pad)
#define WR2        12                // half2 per W row in LDS (10 data + 2 pad)

// 20 FMAs: acc[0..19] += xv * wr[0..19] (wr points into LDS, 16B-aligned)
#define FMA20(acc, xv, wr) do { \
  float4 w0_ = *(const float4*)((wr) + 0);  float4 w1_ = *(const float4*)((wr) + 4); \
  float4 w2_ = *(const float4*)((wr) + 8);  float4 w3_ = *(const float4*)((wr) + 12); \
  float4 w4_ = *(const float4*)((wr) + 16); \
  acc[0]=fmaf(xv,w0_.x,acc[0]);  acc[1]=fmaf(xv,w0_.y,acc[1]);  acc[2]=fmaf(xv,w0_.z,acc[2]);  acc[3]=fmaf(xv,w0_.w,acc[3]); \
  acc[4]=fmaf(xv,w1_.x,acc[4]);  acc[5]=fmaf(xv,w1_.y,acc[5]);  acc[6]=fmaf(xv,w1_.z,acc[6]);  acc[7]=fmaf(xv,w1_.w,acc[7]); \
  acc[8]=fmaf(xv,w2_.x,acc[8]);  acc[9]=fmaf(xv,w2_.y,acc[9]);  acc[10]=fmaf(xv,w2_.z,acc[10]); acc[11]=fmaf(xv,w2_.w,acc[11]); \
  acc[12]=fmaf(xv,w3_.x,acc[12]); acc[13]=fmaf(xv,w3_.y,acc[13]); acc[14]=fmaf(xv,w3_.z,acc[14]); acc[15]=fmaf(xv,w3_.w,acc[15]); \
  acc[16]=fmaf(xv,w4_.x,acc[16]); acc[17]=fmaf(xv,w4_.y,acc[17]); acc[18]=fmaf(xv,w4_.z,acc[18]); acc[19]=fmaf(xv,w4_.w,acc[19]); \
} while (0)

__global__ __launch_bounds__(256) void zero2_kernel(int* __restrict__ cnt, float* __restrict__ g) {
    int i = blockIdx.x * 256 + threadIdx.x;
    int st = gridDim.x * 256;
    for (int k = i; k < NODES; k += st) cnt[k] = 0;
    for (int k = i; k < GRAPHS * HID2; k += st) g[k] = 0.0f;
}

__global__ __launch_bounds__(256) void count_kernel(const int* __restrict__ ei, int* __restrict__ cnt) {
    int e = blockIdx.x * 256 + threadIdx.x;
    if (e < EDGES) atomicAdd(&cnt[ei[EDGES + e]], 1);
}

// Block-wise exclusive scan (Hillis-Steele in LDS).
__global__ __launch_bounds__(256) void scan_block(const int* __restrict__ in, int* __restrict__ outx,
                                                  int* __restrict__ bsum, int n) {
    __shared__ int s[256];
    int t = threadIdx.x, i = blockIdx.x * 256 + t;
    int v = (i < n) ? in[i] : 0;
    s[t] = v; __syncthreads();
    for (int off = 1; off < 256; off <<= 1) {
        int x = (t >= off) ? s[t - off] : 0;
        __syncthreads();
        s[t] += x; __syncthreads();
    }
    if (i < n) outx[i] = s[t] - v;
    if (t == 255 && bsum != nullptr) bsum[blockIdx.x] = s[255];
}

__global__ __launch_bounds__(256) void scan_fixup(int* __restrict__ rs, int* __restrict__ cur,
                                                  const int* __restrict__ bscan) {
    int i = blockIdx.x * 256 + threadIdx.x;
    if (i < NODES) {
        int r = rs[i] + bscan[blockIdx.x];
        rs[i] = r;
        cur[i] = r;
    }
    if (i == 0) rs[NODES] = EDGES;
}

__device__ __forceinline__ void store_row_h(__half* dst, const float* acc) {
    union { __half2 h2[16]; uint4 q[4]; } u;
#pragma unroll
    for (int i = 0; i < 10; ++i) u.h2[i] = __floats2half2_rn(acc[2 * i], acc[2 * i + 1]);
#pragma unroll
    for (int i = 10; i < 16; ++i) u.h2[i] = __floats2half2_rn(0.0f, 0.0f);
    uint4* po = (uint4*)dst;
    po[0] = u.q[0]; po[1] = u.q[1]; po[2] = u.q[2]; po[3] = u.q[3];
}

// Ps[n] = node_attr[n] @ W[0:64];  Pd[n] = node_attr[n] @ W[64:128]  (fp16, 64B rows)
__global__ __launch_bounds__(256) void pn_kernel(const float* __restrict__ node_attr,
                                                 const float* __restrict__ W,
                                                 __half* __restrict__ Ps, __half* __restrict__ Pd) {
    __shared__ float Wss[DF * MSG];
    __shared__ float Wds[DF * MSG];
    for (int i = threadIdx.x; i < DF * MSG; i += 256) {
        Wss[i] = W[i];
        Wds[i] = W[DF * MSG + i];
    }
    __syncthreads();

    int n = blockIdx.x * 256 + threadIdx.x;
    if (n >= NODES) return;

    const float4* nr = (const float4*)(node_attr + (size_t)n * DF);
    float4 x[16];
#pragma unroll
    for (int i = 0; i < 16; ++i) x[i] = nr[i];

    float as[MSG], ad[MSG];
#pragma unroll
    for (int j = 0; j < MSG; ++j) { as[j] = 0.0f; ad[j] = 0.0f; }

#pragma unroll
    for (int k4 = 0; k4 < 16; ++k4) {
        const float* xp = (const float*)&x[k4];
#pragma unroll
        for (int cc = 0; cc < 4; ++cc) {
            int k = k4 * 4 + cc;
            FMA20(as, xp[cc], &Wss[k * MSG]);
            FMA20(ad, xp[cc], &Wds[k * MSG]);
        }
    }

    store_row_h(Ps + (size_t)n * RSTRIDE, as);
    store_row_h(Pd + (size_t)n * RSTRIDE, ad);
}

// Fused edge stage v2: 256 threads, 512-edge tile, 4 K-phases (16 floats each).
// LDS ~21.5 KB -> ~7 blocks/CU for cross-block stage/compute overlap.
// Coalesced stage (4 lanes/edge, 64B contiguous), hfma2 GEMV (2 edges/thread),
// then +Ps[src] and CSR scatter as fully-dirty 64B lines.
__global__ __launch_bounds__(EB_THREADS) void pe_fused_kernel(
    const int* __restrict__ ei,
    const float* __restrict__ edge_attr,
    const float* __restrict__ W, const float* __restrict__ b,
    const __half* __restrict__ Ps,
    int* __restrict__ cur,
    __half* __restrict__ PeP)
{
    __shared__ unsigned int xw[EB_TILE * XW_STRIDE];   // 4608 words = 18432 B
    __shared__ __half2 Wh2[64 * WR2];                  // 3072 B
    __shared__ __half2 bh[10];

    const int t = threadIdx.x;
    const long tile0 = (long)blockIdx.x * EB_TILE;

    // stage W_e (k 0..63, output pairs j 0..9) as half2, rows padded to 12 half2
    for (int i = t; i < 64 * WR2; i += EB_THREADS) {
        int k = i / WR2, j = i - k * WR2;
        __half2 v = __floats2half2_rn(0.0f, 0.0f);
        if (j < 10) v = __floats2half2_rn(W[2 * DF * MSG + k * MSG + 2 * j],
                                          W[2 * DF * MSG + k * MSG + 2 * j + 1]);
        Wh2[i] = v;
    }
    if (t < 10) bh[t] = __floats2half2_rn(b[2 * t], b[2 * t + 1]);

    __half2 acc[EB_EPT][10];
#pragma unroll
    for (int i = 0; i < EB_EPT; ++i)
#pragma unroll
        for (int j = 0; j < 10; ++j) acc[i][j] = __floats2half2_rn(0.0f, 0.0f);

    const float4* ea4 = (const float4*)edge_attr;

#pragma unroll
    for (int ph = 0; ph < NPH; ++ph) {
        __syncthreads();   // xw safe to overwrite (and Wh2 ready on ph==0)
        // stage 16 floats (4 float4) per edge: 4 lanes/edge, 64B contiguous
#pragma unroll
        for (int p = 0; p < 8; ++p) {
            int m = t + EB_THREADS * p;          // 0..2047
            int er = m >> 2, kq = m & 3;
            long ge = tile0 + er;
            if (ge < EDGES) {
                float4 v = ea4[ge * 16 + ph * 4 + kq];
                __half2 a = __floats2half2_rn(v.x, v.y);
                __half2 c = __floats2half2_rn(v.z, v.w);
                xw[er * XW_STRIDE + kq * 2]     = *(unsigned int*)&a;
                xw[er * XW_STRIDE + kq * 2 + 1] = *(unsigned int*)&c;
            }
        }
        __syncthreads();
        // compute: 8 k-pairs in this phase
        for (int kp = 0; kp < 8; ++kp) {
            int k0 = ph * 16 + 2 * kp;
            const __half2* w0 = Wh2 + k0 * WR2;
            const __half2* w1 = Wh2 + (k0 + 1) * WR2;
            __half2 wa[10], wb[10];
#pragma unroll
            for (int j = 0; j < 10; ++j) { wa[j] = w0[j]; wb[j] = w1[j]; }
#pragma unroll
            for (int i = 0; i < EB_EPT; ++i) {
                unsigned int xu = xw[(t + EB_THREADS * i) * XW_STRIDE + kp];
                __half2 xp = *(__half2*)&xu;
                __half2 xl = __low2half2(xp);
                __half2 xh = __high2half2(xp);
#pragma unroll
                for (int j = 0; j < 10; ++j) {
                    acc[i][j] = __hfma2(xl, wa[j], acc[i][j]);
                    acc[i][j] = __hfma2(xh, wb[j], acc[i][j]);
                }
            }
        }
    }

    // epilogue: + bias + Ps[src], CSR scatter
#pragma unroll
    for (int i = 0; i < EB_EPT; ++i) {
        long ge = tile0 + t + EB_THREADS * i;
        if (ge >= EDGES) continue;
        int src = ei[ge];
        int dst = ei[EDGES + ge];
        int p = atomicAdd(&cur[dst], 1);

        const uint4* psq = (const uint4*)(Ps + (size_t)src * RSTRIDE);
        uint4 s0 = psq[0], s1 = psq[1];
        uint2 s2 = *(const uint2*)(psq + 2);
        union Q { uint4 q; __half2 h[4]; };
        union D { uint2 d; __half2 h[2]; };
        Q a0; a0.q = s0; Q a1; a1.q = s1; D a2; a2.d = s2;
        Q o0, o1; D o2;
#pragma unroll
        for (int j = 0; j < 4; ++j) o0.h[j] = __hadd2(__hadd2(acc[i][j], bh[j]), a0.h[j]);
#pragma unroll
        for (int j = 0; j < 4; ++j) o1.h[j] = __hadd2(__hadd2(acc[i][4 + j], bh[4 + j]), a1.h[j]);
#pragma unroll
        for (int j = 0; j < 2; ++j) o2.h[j] = __hadd2(__hadd2(acc[i][8 + j], bh[8 + j]), a2.h[j]);

        __half* orow = PeP + (size_t)p * RSTRIDE;
        *(uint4*)(orow)      = o0.q;
        *(uint4*)(orow + 8)  = o1.q;
        *(uint2*)(orow + 16) = o2.d;
        *(uint2*)(orow + 20) = make_uint2(0u, 0u);
        *(uint4*)(orow + 24) = make_uint4(0u, 0u, 0u, 0u);
    }
}

// Node-centric aggregate: 4 lanes per node stream contiguous fp16 CSR rows,
// acc += relu(row + Pd[node]); quad shfl-reduce; 20->20->10 MLP; atomic into gacc.
__global__ __launch_bounds__(256) void agg_kernel(const int* __restrict__ rs,
                                                  const __half* __restrict__ PeP,
                                                  const __half* __restrict__ Pd,
                                                  const float* __restrict__ W1, const float* __restrict__ b1,
                                                  const float* __restrict__ W2, const float* __restrict__ b2,
                                                  const int* __restrict__ batch, float* __restrict__ gacc) {
    __shared__ float W1s[MSG * MSG], W2s[MSG * HID2], b1s[MSG], b2s[HID2];
    for (int i = threadIdx.x; i < MSG * MSG; i += 256) W1s[i] = W1[i];
    for (int i = threadIdx.x; i < MSG * HID2; i += 256) W2s[i] = W2[i];
    if (threadIdx.x < MSG) b1s[threadIdx.x] = b1[threadIdx.x];
    if (threadIdx.x < HID2) b2s[threadIdx.x] = b2[threadIdx.x];
    __syncthreads();

    int t = threadIdx.x;
    int node = blockIdx.x * 64 + (t >> 2);
    int lane = t & 3;

    float acc[MSG];
#pragma unroll
    for (int j = 0; j < MSG; ++j) acc[j] = 0.0f;

    if (node < NODES) {
        int s0 = rs[node];
        int deg = rs[node + 1] - s0;

        float pd[MSG];
        {
            const uint4* pr = (const uint4*)(Pd + (size_t)node * RSTRIDE);
            union { uint4 q; __half2 h2[4]; } a0, a1;
            union { uint2 q; __half2 h2[2]; } a2;
            a0.q = pr[0]; a1.q = pr[1]; a2.q = *(const uint2*)(pr + 2);
#pragma unroll
            for (int i = 0; i < 4; ++i) {
                float2 f = __half22float2(a0.h2[i]);
                pd[2 * i] = f.x; pd[2 * i + 1] = f.y;
            }
#pragma unroll
            for (int i = 0; i < 4; ++i) {
                float2 f = __half22float2(a1.h2[i]);
                pd[8 + 2 * i] = f.x; pd[9 + 2 * i] = f.y;
            }
#pragma unroll
            for (int i = 0; i < 2; ++i) {
                float2 f = __half22float2(a2.h2[i]);
                pd[16 + 2 * i] = f.x; pd[17 + 2 * i] = f.y;
            }
        }

        for (int i = lane; i < deg; i += 4) {
            const uint4* rp = (const uint4*)(PeP + (size_t)(s0 + i) * RSTRIDE);
            uint4 q0 = rp[0], q1 = rp[1];
            uint2 q2 = *(const uint2*)(rp + 2);
            union { uint4 q; __half2 h2[4]; } a0, a1;
            union { uint2 q; __half2 h2[2]; } a2;
            a0.q = q0; a1.q = q1; a2.q = q2;
#pragma unroll
            for (int k = 0; k < 4; ++k) {
                float2 f = __half22float2(a0.h2[k]);
                acc[2 * k]     += fmaxf(f.x + pd[2 * k], 0.0f);
                acc[2 * k + 1] += fmaxf(f.y + pd[2 * k + 1], 0.0f);
            }
#pragma unroll
            for (int k = 0; k < 4; ++k) {
                float2 f = __half22float2(a1.h2[k]);
                acc[8 + 2 * k] += fmaxf(f.x + pd[8 + 2 * k], 0.0f);
                acc[9 + 2 * k] += fmaxf(f.y + pd[9 + 2 * k], 0.0f);
            }
#pragma unroll
            for (int k = 0; k < 2; ++k) {
                float2 f = __half22float2(a2.h2[k]);
                acc[16 + 2 * k] += fmaxf(f.x + pd[16 + 2 * k], 0.0f);
                acc[17 + 2 * k] += fmaxf(f.y + pd[17 + 2 * k], 0.0f);
            }
        }
    }

#pragma unroll
    for (int j = 0; j < MSG; ++j) acc[j] += __shfl_xor(acc[j], 1);
#pragma unroll
    for (int j = 0; j < MSG; ++j) acc[j] += __shfl_xor(acc[j], 2);

    if (node < NODES && lane == 0) {
        float t1[MSG];
#pragma unroll
        for (int j = 0; j < MSG; ++j) t1[j] = b1s[j];
#pragma unroll
        for (int k = 0; k < MSG; ++k)
#pragma unroll
            for (int j = 0; j < MSG; ++j) t1[j] = fmaf(acc[k], W1s[k * MSG + j], t1[j]);
#pragma unroll
        for (int j = 0; j < MSG; ++j) t1[j] = fmaxf(t1[j], 0.0f);

        float t2[HID2];
#pragma unroll
        for (int m = 0; m < HID2; ++m) t2[m] = b2s[m];
#pragma unroll
        for (int k = 0; k < MSG; ++k)
#pragma unroll
            for (int m = 0; m < HID2; ++m) t2[m] = fmaf(t1[k], W2s[k * HID2 + m], t2[m]);

        int g = batch[node];
        float* gr = gacc + (size_t)g * HID2;
#pragma unroll
        for (int m = 0; m < HID2; ++m) atomicAdd(gr + m, fmaxf(t2[m], 0.0f));
    }
}

__global__ void graph_kernel(const float* __restrict__ gacc,
                             const float* __restrict__ W3, const float* __restrict__ b3,
                             const float* __restrict__ W4, const float* __restrict__ b4,
                             float* __restrict__ out) {
    int g = blockIdx.x * blockDim.x + threadIdx.x;
    if (g >= GRAPHS) return;

    float h[HID2];
#pragma unroll
    for (int m = 0; m < HID2; ++m) h[m] = gacc[(size_t)g * HID2 + m];

    float t[HID2];
#pragma unroll
    for (int j = 0; j < HID2; ++j) {
        float s = b3[j];
#pragma unroll
        for (int k = 0; k < HID2; ++k) s = fmaf(h[k], W3[k * HID2 + j], s);
        t[j] = fmaxf(s, 0.0f);
    }
    float s = b4[0];
#pragma unroll
    for (int k = 0; k < HID2; ++k) s = fmaf(t[k], W4[k], s);
    out[g] = s;
}

extern "C" void kernel_launch(void* const* d_in, const int* in_sizes, int n_in,
                              void* d_out, int out_size, void* d_ws, size_t ws_size,
                              hipStream_t stream) {
    const int*   ei        = (const int*)  d_in[0];
    const float* node_attr = (const float*)d_in[1];
    const float* edge_attr = (const float*)d_in[2];
    const int*   batch     = (const int*)  d_in[3];
    const float* W_mpl     = (const float*)d_in[4];
    const float* b_mpl     = (const float*)d_in[5];
    const float* W1        = (const float*)d_in[6];
    const float* b1        = (const float*)d_in[7];
    const float* W2        = (const float*)d_in[8];
    const float* b2        = (const float*)d_in[9];
    const float* W3        = (const float*)d_in[10];
    const float* b3        = (const float*)d_in[11];
    const float* W4        = (const float*)d_in[12];
    const float* b4        = (const float*)d_in[13];
    float* out = (float*)d_out;

    // workspace layout (all offsets multiples of 64B)
    __half* PeP = (__half*)d_ws;                          // E*32 halves (51.2 MB), CSR-ordered
    __half* Ps  = PeP + (size_t)EDGES * RSTRIDE;          // N*32 halves (3.2 MB)
    __half* Pd  = Ps + (size_t)NODES * RSTRIDE;           // N*32 halves (3.2 MB)
    float* gacc = (float*)(Pd + (size_t)NODES * RSTRIDE); // G*10
    int* cnt    = (int*)(gacc + GRAPHS * HID2);           // N (padded 50176)
    int* rs     = cnt + 50176;                            // N+1 (padded)
    int* cur    = rs + 50176;                             // N (padded)
    int* bsum   = cur + 50176;                            // 256
    int* bscan  = bsum + 256;                             // 256

    int egrid  = (EDGES + 255) / 256;             // 3125
    int ngrid  = NB1;                             // 196
    int pegrid = (EDGES + EB_TILE - 1) / EB_TILE; // 1563

    hipLaunchKernelGGL(zero2_kernel, dim3(256), dim3(256), 0, stream, cnt, gacc);
    hipLaunchKernelGGL(count_kernel, dim3(egrid), dim3(256), 0, stream, ei, cnt);
    hipLaunchKernelGGL(scan_block, dim3(ngrid), dim3(256), 0, stream, cnt, rs, bsum, NODES);
    hipLaunchKernelGGL(scan_block, dim3(1), dim3(256), 0, stream, bsum, bscan, (int*)nullptr, NB1);
    hipLaunchKernelGGL(scan_fixup, dim3(ngrid), dim3(256), 0, stream, rs, cur, bscan);
    hipLaunchKernelGGL(pn_kernel, dim3(ngrid), dim3(256), 0, stream, node_attr, W_mpl, Ps, Pd);
    hipLaunchKernelGGL(pe_fused_kernel, dim3(pegrid), dim3(EB_THREADS), 0, stream,
                       ei, edge_attr, W_mpl, b_mpl, Ps, cur, PeP);
    hipLaunchKernelGGL(agg_kernel, dim3((NODES + 63) / 64), dim3(256), 0, stream,
                       rs, PeP, Pd, W1, b1, W2, b2, batch, gacc);
    hipLaunchKernelGGL(graph_kernel, dim3(2), dim3(256), 0, stream, gacc, W3, b3, W4, b4, out);
}

// Round 9
// 421.583 us; speedup vs baseline: 1.5086x; 1.5086x over previous
//
#include <hip/hip_runtime.h>
#include <hip/hip_fp16.h>

#define DF 64
#define MSG 20
#define HID2 10
#define NODES 50000
#define EDGES 800000
#define GRAPHS 512
#define RSTRIDE 32   // halves per padded output row = 64 B (one cache line)
#define NB1 ((NODES + 255) / 256)   // 196

// edge-stage tiling
#define EB_THREADS 256
#define EB_TILE    512               // edges per block
#define EB_EPT     2                 // edges per thread
#define NPH        4                 // K phases (16 floats each)
#define XW_STRIDE  9                 // LDS words per edge per phase (8 data + 1 pad)
#define WR2        12                // half2 per W row in LDS (10 data + 2 pad)

// 20 FMAs: acc[0..19] += xv * wr[0..19] (wr points into LDS, 16B-aligned)
#define FMA20(acc, xv, wr) do { \
  float4 w0_ = *(const float4*)((wr) + 0);  float4 w1_ = *(const float4*)((wr) + 4); \
  float4 w2_ = *(const float4*)((wr) + 8);  float4 w3_ = *(const float4*)((wr) + 12); \
  float4 w4_ = *(const float4*)((wr) + 16); \
  acc[0]=fmaf(xv,w0_.x,acc[0]);  acc[1]=fmaf(xv,w0_.y,acc[1]);  acc[2]=fmaf(xv,w0_.z,acc[2]);  acc[3]=fmaf(xv,w0_.w,acc[3]); \
  acc[4]=fmaf(xv,w1_.x,acc[4]);  acc[5]=fmaf(xv,w1_.y,acc[5]);  acc[6]=fmaf(xv,w1_.z,acc[6]);  acc[7]=fmaf(xv,w1_.w,acc[7]); \
  acc[8]=fmaf(xv,w2_.x,acc[8]);  acc[9]=fmaf(xv,w2_.y,acc[9]);  acc[10]=fmaf(xv,w2_.z,acc[10]); acc[11]=fmaf(xv,w2_.w,acc[11]); \
  acc[12]=fmaf(xv,w3_.x,acc[12]); acc[13]=fmaf(xv,w3_.y,acc[13]); acc[14]=fmaf(xv,w3_.z,acc[14]); acc[15]=fmaf(xv,w3_.w,acc[15]); \
  acc[16]=fmaf(xv,w4_.x,acc[16]); acc[17]=fmaf(xv,w4_.y,acc[17]); acc[18]=fmaf(xv,w4_.z,acc[18]); acc[19]=fmaf(xv,w4_.w,acc[19]); \
} while (0)

__global__ __launch_bounds__(256) void zero2_kernel(int* __restrict__ cnt, float* __restrict__ g) {
    int i = blockIdx.x * 256 + threadIdx.x;
    int st = gridDim.x * 256;
    for (int k = i; k < NODES; k += st) cnt[k] = 0;
    for (int k = i; k < GRAPHS * HID2; k += st) g[k] = 0.0f;
}

__global__ __launch_bounds__(256) void count_kernel(const int* __restrict__ ei, int* __restrict__ cnt) {
    int e = blockIdx.x * 256 + threadIdx.x;
    if (e < EDGES) atomicAdd(&cnt[ei[EDGES + e]], 1);
}

// Block-wise exclusive scan (Hillis-Steele in LDS).
__global__ __launch_bounds__(256) void scan_block(const int* __restrict__ in, int* __restrict__ outx,
                                                  int* __restrict__ bsum, int n) {
    __shared__ int s[256];
    int t = threadIdx.x, i = blockIdx.x * 256 + t;
    int v = (i < n) ? in[i] : 0;
    s[t] = v; __syncthreads();
    for (int off = 1; off < 256; off <<= 1) {
        int x = (t >= off) ? s[t - off] : 0;
        __syncthreads();
        s[t] += x; __syncthreads();
    }
    if (i < n) outx[i] = s[t] - v;
    if (t == 255 && bsum != nullptr) bsum[blockIdx.x] = s[255];
}

__device__ __forceinline__ void store_row_h(__half* dst, const float* acc) {
    union { __half2 h2[16]; uint4 q[4]; } u;
#pragma unroll
    for (int i = 0; i < 10; ++i) u.h2[i] = __floats2half2_rn(acc[2 * i], acc[2 * i + 1]);
#pragma unroll
    for (int i = 10; i < 16; ++i) u.h2[i] = __floats2half2_rn(0.0f, 0.0f);
    uint4* po = (uint4*)dst;
    po[0] = u.q[0]; po[1] = u.q[1]; po[2] = u.q[2]; po[3] = u.q[3];
}

// Fused: scan fixup (rs += bscan, cur = rs) AND pn projections (independent work,
// same 196x256 grid) -> one launch fewer.
__global__ __launch_bounds__(256) void fixup_pn_kernel(int* __restrict__ rs, int* __restrict__ cur,
                                                       const int* __restrict__ bscan,
                                                       const float* __restrict__ node_attr,
                                                       const float* __restrict__ W,
                                                       __half* __restrict__ Ps, __half* __restrict__ Pd) {
    int i = blockIdx.x * 256 + threadIdx.x;
    if (i < NODES) {
        int r = rs[i] + bscan[blockIdx.x];
        rs[i] = r;
        cur[i] = r;
    }
    if (i == 0) rs[NODES] = EDGES;

    __shared__ float Wss[DF * MSG];
    __shared__ float Wds[DF * MSG];
    for (int k = threadIdx.x; k < DF * MSG; k += 256) {
        Wss[k] = W[k];
        Wds[k] = W[DF * MSG + k];
    }
    __syncthreads();

    int n = i;
    if (n >= NODES) return;

    const float4* nr = (const float4*)(node_attr + (size_t)n * DF);
    float4 x[16];
#pragma unroll
    for (int q = 0; q < 16; ++q) x[q] = nr[q];

    float as[MSG], ad[MSG];
#pragma unroll
    for (int j = 0; j < MSG; ++j) { as[j] = 0.0f; ad[j] = 0.0f; }

#pragma unroll
    for (int k4 = 0; k4 < 16; ++k4) {
        const float* xp = (const float*)&x[k4];
#pragma unroll
        for (int cc = 0; cc < 4; ++cc) {
            int k = k4 * 4 + cc;
            FMA20(as, xp[cc], &Wss[k * MSG]);
            FMA20(ad, xp[cc], &Wds[k * MSG]);
        }
    }

    store_row_h(Ps + (size_t)n * RSTRIDE, as);
    store_row_h(Pd + (size_t)n * RSTRIDE, ad);
}

// Fused edge stage v3: 256 threads, 512-edge tile, 4 K-phases (16 floats each).
// Register-disciplined: launch_bounds(256,4) caps at 128 VGPR; phase loop NOT
// unrolled; staging loads batched into 8 regs then stored. Coalesced stage
// (4 lanes/edge, 64B contiguous = m13 streaming pattern), hfma2 GEMV
// (2 edges/thread, W read once per pair), then +bias+Ps[src] and CSR scatter
// as fully-dirty 64B lines.
__global__ __launch_bounds__(EB_THREADS, 4) void pe_fused_kernel(
    const int* __restrict__ ei,
    const float* __restrict__ edge_attr,
    const float* __restrict__ W, const float* __restrict__ b,
    const __half* __restrict__ Ps,
    int* __restrict__ cur,
    __half* __restrict__ PeP)
{
    __shared__ unsigned int xw[EB_TILE * XW_STRIDE];   // 4608 words = 18432 B
    __shared__ __half2 Wh2[64 * WR2];                  // 3072 B
    __shared__ __half2 bh[10];

    const int t = threadIdx.x;
    const long tile0 = (long)blockIdx.x * EB_TILE;

    // stage W_e (k 0..63, output pairs j 0..9) as half2, rows padded to 12 half2
    for (int i = t; i < 64 * WR2; i += EB_THREADS) {
        int k = i / WR2, j = i - k * WR2;
        __half2 v = __floats2half2_rn(0.0f, 0.0f);
        if (j < 10) v = __floats2half2_rn(W[2 * DF * MSG + k * MSG + 2 * j],
                                          W[2 * DF * MSG + k * MSG + 2 * j + 1]);
        Wh2[i] = v;
    }
    if (t < 10) bh[t] = __floats2half2_rn(b[2 * t], b[2 * t + 1]);

    __half2 acc[EB_EPT][10];
#pragma unroll
    for (int i = 0; i < EB_EPT; ++i)
#pragma unroll
        for (int j = 0; j < 10; ++j) acc[i][j] = __floats2half2_rn(0.0f, 0.0f);

    const float4* ea4 = (const float4*)edge_attr;

#pragma unroll 1
    for (int ph = 0; ph < NPH; ++ph) {
        __syncthreads();   // xw safe to overwrite (and Wh2/bh ready on ph==0)

        // batch the 8 staging loads into registers (bounded live set, 8 in flight)
        float4 xv[8];
#pragma unroll
        for (int p = 0; p < 8; ++p) {
            int m = t + EB_THREADS * p;          // 0..2047
            long ge = tile0 + (m >> 2);
            if (ge < EDGES) xv[p] = ea4[ge * 16 + ph * 4 + (m & 3)];
            else            xv[p] = make_float4(0.f, 0.f, 0.f, 0.f);
        }
#pragma unroll
        for (int p = 0; p < 8; ++p) {
            int m = t + EB_THREADS * p;
            int er = m >> 2, kq = m & 3;
            __half2 a = __floats2half2_rn(xv[p].x, xv[p].y);
            __half2 c = __floats2half2_rn(xv[p].z, xv[p].w);
            xw[er * XW_STRIDE + kq * 2]     = *(unsigned int*)&a;
            xw[er * XW_STRIDE + kq * 2 + 1] = *(unsigned int*)&c;
        }
        __syncthreads();

        // compute: 8 k-pairs in this phase
        for (int kp = 0; kp < 8; ++kp) {
            int k0 = ph * 16 + 2 * kp;
            const __half2* w0 = Wh2 + k0 * WR2;
            const __half2* w1 = Wh2 + (k0 + 1) * WR2;
            __half2 wa[10], wb[10];
#pragma unroll
            for (int j = 0; j < 10; ++j) { wa[j] = w0[j]; wb[j] = w1[j]; }
#pragma unroll
            for (int i = 0; i < EB_EPT; ++i) {
                unsigned int xu = xw[(t + EB_THREADS * i) * XW_STRIDE + kp];
                __half2 xp = *(__half2*)&xu;
                __half2 xl = __low2half2(xp);
                __half2 xh = __high2half2(xp);
#pragma unroll
                for (int j = 0; j < 10; ++j) {
                    acc[i][j] = __hfma2(xl, wa[j], acc[i][j]);
                    acc[i][j] = __hfma2(xh, wb[j], acc[i][j]);
                }
            }
        }
    }

    // epilogue: + bias + Ps[src], CSR scatter
#pragma unroll 1
    for (int i = 0; i < EB_EPT; ++i) {
        long ge = tile0 + t + EB_THREADS * i;
        if (ge >= EDGES) continue;
        int src = ei[ge];
        int dst = ei[EDGES + ge];
        int p = atomicAdd(&cur[dst], 1);

        const uint4* psq = (const uint4*)(Ps + (size_t)src * RSTRIDE);
        uint4 s0 = psq[0], s1 = psq[1];
        uint2 s2 = *(const uint2*)(psq + 2);
        union Q { uint4 q; __half2 h[4]; };
        union D { uint2 d; __half2 h[2]; };
        Q a0; a0.q = s0; Q a1; a1.q = s1; D a2; a2.d = s2;
        Q o0, o1; D o2;
#pragma unroll
        for (int j = 0; j < 4; ++j) o0.h[j] = __hadd2(__hadd2(acc[i][j], bh[j]), a0.h[j]);
#pragma unroll
        for (int j = 0; j < 4; ++j) o1.h[j] = __hadd2(__hadd2(acc[i][4 + j], bh[4 + j]), a1.h[j]);
#pragma unroll
        for (int j = 0; j < 2; ++j) o2.h[j] = __hadd2(__hadd2(acc[i][8 + j], bh[8 + j]), a2.h[j]);

        __half* orow = PeP + (size_t)p * RSTRIDE;
        *(uint4*)(orow)      = o0.q;
        *(uint4*)(orow + 8)  = o1.q;
        *(uint2*)(orow + 16) = o2.d;
        *(uint2*)(orow + 20) = make_uint2(0u, 0u);
        *(uint4*)(orow + 24) = make_uint4(0u, 0u, 0u, 0u);
    }
}

// Node-centric aggregate: 4 lanes per node stream contiguous fp16 CSR rows,
// acc += relu(row + Pd[node]); quad shfl-reduce; 20->20->10 MLP; atomic into gacc.
__global__ __launch_bounds__(256) void agg_kernel(const int* __restrict__ rs,
                                                  const __half* __restrict__ PeP,
                                                  const __half* __restrict__ Pd,
                                                  const float* __restrict__ W1, const float* __restrict__ b1,
                                                  const float* __restrict__ W2, const float* __restrict__ b2,
                                                  const int* __restrict__ batch, float* __restrict__ gacc) {
    __shared__ float W1s[MSG * MSG], W2s[MSG * HID2], b1s[MSG], b2s[HID2];
    for (int i = threadIdx.x; i < MSG * MSG; i += 256) W1s[i] = W1[i];
    for (int i = threadIdx.x; i < MSG * HID2; i += 256) W2s[i] = W2[i];
    if (threadIdx.x < MSG) b1s[threadIdx.x] = b1[threadIdx.x];
    if (threadIdx.x < HID2) b2s[threadIdx.x] = b2[threadIdx.x];
    __syncthreads();

    int t = threadIdx.x;
    int node = blockIdx.x * 64 + (t >> 2);
    int lane = t & 3;

    float acc[MSG];
#pragma unroll
    for (int j = 0; j < MSG; ++j) acc[j] = 0.0f;

    if (node < NODES) {
        int s0 = rs[node];
        int deg = rs[node + 1] - s0;

        float pd[MSG];
        {
            const uint4* pr = (const uint4*)(Pd + (size_t)node * RSTRIDE);
            union { uint4 q; __half2 h2[4]; } a0, a1;
            union { uint2 q; __half2 h2[2]; } a2;
            a0.q = pr[0]; a1.q = pr[1]; a2.q = *(const uint2*)(pr + 2);
#pragma unroll
            for (int i = 0; i < 4; ++i) {
                float2 f = __half22float2(a0.h2[i]);
                pd[2 * i] = f.x; pd[2 * i + 1] = f.y;
            }
#pragma unroll
            for (int i = 0; i < 4; ++i) {
                float2 f = __half22float2(a1.h2[i]);
                pd[8 + 2 * i] = f.x; pd[9 + 2 * i] = f.y;
            }
#pragma unroll
            for (int i = 0; i < 2; ++i) {
                float2 f = __half22float2(a2.h2[i]);
                pd[16 + 2 * i] = f.x; pd[17 + 2 * i] = f.y;
            }
        }

        for (int i = lane; i < deg; i += 4) {
            const uint4* rp = (const uint4*)(PeP + (size_t)(s0 + i) * RSTRIDE);
            uint4 q0 = rp[0], q1 = rp[1];
            uint2 q2 = *(const uint2*)(rp + 2);
            union { uint4 q; __half2 h2[4]; } a0, a1;
            union { uint2 q; __half2 h2[2]; } a2;
            a0.q = q0; a1.q = q1; a2.q = q2;
#pragma unroll
            for (int k = 0; k < 4; ++k) {
                float2 f = __half22float2(a0.h2[k]);
                acc[2 * k]     += fmaxf(f.x + pd[2 * k], 0.0f);
                acc[2 * k + 1] += fmaxf(f.y + pd[2 * k + 1], 0.0f);
            }
#pragma unroll
            for (int k = 0; k < 4; ++k) {
                float2 f = __half22float2(a1.h2[k]);
                acc[8 + 2 * k] += fmaxf(f.x + pd[8 + 2 * k], 0.0f);
                acc[9 + 2 * k] += fmaxf(f.y + pd[9 + 2 * k], 0.0f);
            }
#pragma unroll
            for (int k = 0; k < 2; ++k) {
                float2 f = __half22float2(a2.h2[k]);
                acc[16 + 2 * k] += fmaxf(f.x + pd[16 + 2 * k], 0.0f);
                acc[17 + 2 * k] += fmaxf(f.y + pd[17 + 2 * k], 0.0f);
            }
        }
    }

#pragma unroll
    for (int j = 0; j < MSG; ++j) acc[j] += __shfl_xor(acc[j], 1);
#pragma unroll
    for (int j = 0; j < MSG; ++j) acc[j] += __shfl_xor(acc[j], 2);

    if (node < NODES && lane == 0) {
        float t1[MSG];
#pragma unroll
        for (int j = 0; j < MSG; ++j) t1[j] = b1s[j];
#pragma unroll
        for (int k = 0; k < MSG; ++k)
#pragma unroll
            for (int j = 0; j < MSG; ++j) t1[j] = fmaf(acc[k], W1s[k * MSG + j], t1[j]);
#pragma unroll
        for (int j = 0; j < MSG; ++j) t1[j] = fmaxf(t1[j], 0.0f);

        float t2[HID2];
#pragma unroll
        for (int m = 0; m < HID2; ++m) t2[m] = b2s[m];
#pragma unroll
        for (int k = 0; k < MSG; ++k)
#pragma unroll
            for (int m = 0; m < HID2; ++m) t2[m] = fmaf(t1[k], W2s[k * HID2 + m], t2[m]);

        int g = batch[node];
        float* gr = gacc + (size_t)g * HID2;
#pragma unroll
        for (int m = 0; m < HID2; ++m) atomicAdd(gr + m, fmaxf(t2[m], 0.0f));
    }
}

__global__ void graph_kernel(const float* __restrict__ gacc,
                             const float* __restrict__ W3, const float* __restrict__ b3,
                             const float* __restrict__ W4, const float* __restrict__ b4,
                             float* __restrict__ out) {
    int g = blockIdx.x * blockDim.x + threadIdx.x;
    if (g >= GRAPHS) return;

    float h[HID2];
#pragma unroll
    for (int m = 0; m < HID2; ++m) h[m] = gacc[(size_t)g * HID2 + m];

    float t[HID2];
#pragma unroll
    for (int j = 0; j < HID2; ++j) {
        float s = b3[j];
#pragma unroll
        for (int k = 0; k < HID2; ++k) s = fmaf(h[k], W3[k * HID2 + j], s);
        t[j] = fmaxf(s, 0.0f);
    }
    float s = b4[0];
#pragma unroll
    for (int k = 0; k < HID2; ++k) s = fmaf(t[k], W4[k], s);
    out[g] = s;
}

extern "C" void kernel_launch(void* const* d_in, const int* in_sizes, int n_in,
                              void* d_out, int out_size, void* d_ws, size_t ws_size,
                              hipStream_t stream) {
    const int*   ei        = (const int*)  d_in[0];
    const float* node_attr = (const float*)d_in[1];
    const float* edge_attr = (const float*)d_in[2];
    const int*   batch     = (const int*)  d_in[3];
    const float* W_mpl     = (const float*)d_in[4];
    const float* b_mpl     = (const float*)d_in[5];
    const float* W1        = (const float*)d_in[6];
    const float* b1        = (const float*)d_in[7];
    const float* W2        = (const float*)d_in[8];
    const float* b2        = (const float*)d_in[9];
    const float* W3        = (const float*)d_in[10];
    const float* b3        = (const float*)d_in[11];
    const float* W4        = (const float*)d_in[12];
    const float* b4        = (const float*)d_in[13];
    float* out = (float*)d_out;

    // workspace layout (all offsets multiples of 64B)
    __half* PeP = (__half*)d_ws;                          // E*32 halves (51.2 MB), CSR-ordered
    __half* Ps  = PeP + (size_t)EDGES * RSTRIDE;          // N*32 halves (3.2 MB)
    __half* Pd  = Ps + (size_t)NODES * RSTRIDE;           // N*32 halves (3.2 MB)
    float* gacc = (float*)(Pd + (size_t)NODES * RSTRIDE); // G*10
    int* cnt    = (int*)(gacc + GRAPHS * HID2);           // N (padded 50176)
    int* rs     = cnt + 50176;                            // N+1 (padded)
    int* cur    = rs + 50176;                             // N (padded)
    int* bsum   = cur + 50176;                            // 256
    int* bscan  = bsum + 256;                             // 256

    int egrid  = (EDGES + 255) / 256;             // 3125
    int ngrid  = NB1;                             // 196
    int pegrid = (EDGES + EB_TILE - 1) / EB_TILE; // 1563

    hipLaunchKernelGGL(zero2_kernel, dim3(256), dim3(256), 0, stream, cnt, gacc);
    hipLaunchKernelGGL(count_kernel, dim3(egrid), dim3(256), 0, stream, ei, cnt);
    hipLaunchKernelGGL(scan_block, dim3(ngrid), dim3(256), 0, stream, cnt, rs, bsum, NODES);
    hipLaunchKernelGGL(scan_block, dim3(1), dim3(256), 0, stream, bsum, bscan, (int*)nullptr, NB1);
    hipLaunchKernelGGL(fixup_pn_kernel, dim3(ngrid), dim3(256), 0, stream,
                       rs, cur, bscan, node_attr, W_mpl, Ps, Pd);
    hipLaunchKernelGGL(pe_fused_kernel, dim3(pegrid), dim3(EB_THREADS), 0, stream,
                       ei, edge_attr, W_mpl, b_mpl, Ps, cur, PeP);
    hipLaunchKernelGGL(agg_kernel, dim3((NODES + 63) / 64), dim3(256), 0, stream,
                       rs, PeP, Pd, W1, b1, W2, b2, batch, gacc);
    hipLaunchKernelGGL(graph_kernel, dim3(2), dim3(256), 0, stream, gacc, W3, b3, W4, b4, out);
}

// Round 10
// 250.328 us; speedup vs baseline: 2.5406x; 1.6841x over previous
//
#include <hip/hip_runtime.h>
#include <hip/hip_fp16.h>

#define DF 64
#define MSG 20
#define HID2 10
#define NODES 50000
#define EDGES 800000
#define GRAPHS 512
#define RSTRIDE 32   // halves per padded output row = 64 B (one cache line)
#define NB1 ((NODES + 255) / 256)   // 196
#define WR2 12       // half2 per W row in LDS (10 data + 2 pad) = 48 B

// 20 FMAs: acc[0..19] += xv * wr[0..19] (wr points into LDS, 16B-aligned)
#define FMA20(acc, xv, wr) do { \
  float4 w0_ = *(const float4*)((wr) + 0);  float4 w1_ = *(const float4*)((wr) + 4); \
  float4 w2_ = *(const float4*)((wr) + 8);  float4 w3_ = *(const float4*)((wr) + 12); \
  float4 w4_ = *(const float4*)((wr) + 16); \
  acc[0]=fmaf(xv,w0_.x,acc[0]);  acc[1]=fmaf(xv,w0_.y,acc[1]);  acc[2]=fmaf(xv,w0_.z,acc[2]);  acc[3]=fmaf(xv,w0_.w,acc[3]); \
  acc[4]=fmaf(xv,w1_.x,acc[4]);  acc[5]=fmaf(xv,w1_.y,acc[5]);  acc[6]=fmaf(xv,w1_.z,acc[6]);  acc[7]=fmaf(xv,w1_.w,acc[7]); \
  acc[8]=fmaf(xv,w2_.x,acc[8]);  acc[9]=fmaf(xv,w2_.y,acc[9]);  acc[10]=fmaf(xv,w2_.z,acc[10]); acc[11]=fmaf(xv,w2_.w,acc[11]); \
  acc[12]=fmaf(xv,w3_.x,acc[12]); acc[13]=fmaf(xv,w3_.y,acc[13]); acc[14]=fmaf(xv,w3_.z,acc[14]); acc[15]=fmaf(xv,w3_.w,acc[15]); \
  acc[16]=fmaf(xv,w4_.x,acc[16]); acc[17]=fmaf(xv,w4_.y,acc[17]); acc[18]=fmaf(xv,w4_.z,acc[18]); acc[19]=fmaf(xv,w4_.w,acc[19]); \
} while (0)

__global__ __launch_bounds__(256) void zero2_kernel(int* __restrict__ cnt, float* __restrict__ g) {
    int i = blockIdx.x * 256 + threadIdx.x;
    int st = gridDim.x * 256;
    for (int k = i; k < NODES; k += st) cnt[k] = 0;
    for (int k = i; k < GRAPHS * HID2; k += st) g[k] = 0.0f;
}

__global__ __launch_bounds__(256) void count_kernel(const int* __restrict__ ei, int* __restrict__ cnt) {
    int e = blockIdx.x * 256 + threadIdx.x;
    if (e < EDGES) atomicAdd(&cnt[ei[EDGES + e]], 1);
}

// Block-wise exclusive scan (Hillis-Steele in LDS).
__global__ __launch_bounds__(256) void scan_block(const int* __restrict__ in, int* __restrict__ outx,
                                                  int* __restrict__ bsum, int n) {
    __shared__ int s[256];
    int t = threadIdx.x, i = blockIdx.x * 256 + t;
    int v = (i < n) ? in[i] : 0;
    s[t] = v; __syncthreads();
    for (int off = 1; off < 256; off <<= 1) {
        int x = (t >= off) ? s[t - off] : 0;
        __syncthreads();
        s[t] += x; __syncthreads();
    }
    if (i < n) outx[i] = s[t] - v;
    if (t == 255 && bsum != nullptr) bsum[blockIdx.x] = s[255];
}

__device__ __forceinline__ void store_row_h(__half* dst, const float* acc) {
    union { __half2 h2[16]; uint4 q[4]; } u;
#pragma unroll
    for (int i = 0; i < 10; ++i) u.h2[i] = __floats2half2_rn(acc[2 * i], acc[2 * i + 1]);
#pragma unroll
    for (int i = 10; i < 16; ++i) u.h2[i] = __floats2half2_rn(0.0f, 0.0f);
    uint4* po = (uint4*)dst;
    po[0] = u.q[0]; po[1] = u.q[1]; po[2] = u.q[2]; po[3] = u.q[3];
}

// Fused: scan fixup (rs += bscan, cur = rs) AND pn projections (same 196x256 grid).
__global__ __launch_bounds__(256) void fixup_pn_kernel(int* __restrict__ rs, int* __restrict__ cur,
                                                       const int* __restrict__ bscan,
                                                       const float* __restrict__ node_attr,
                                                       const float* __restrict__ W,
                                                       __half* __restrict__ Ps, __half* __restrict__ Pd) {
    int i = blockIdx.x * 256 + threadIdx.x;
    if (i < NODES) {
        int r = rs[i] + bscan[blockIdx.x];
        rs[i] = r;
        cur[i] = r;
    }
    if (i == 0) rs[NODES] = EDGES;

    __shared__ float Wss[DF * MSG];
    __shared__ float Wds[DF * MSG];
    for (int k = threadIdx.x; k < DF * MSG; k += 256) {
        Wss[k] = W[k];
        Wds[k] = W[DF * MSG + k];
    }
    __syncthreads();

    int n = i;
    if (n >= NODES) return;

    const float4* nr = (const float4*)(node_attr + (size_t)n * DF);
    float4 x[16];
#pragma unroll
    for (int q = 0; q < 16; ++q) x[q] = nr[q];

    float as[MSG], ad[MSG];
#pragma unroll
    for (int j = 0; j < MSG; ++j) { as[j] = 0.0f; ad[j] = 0.0f; }

#pragma unroll
    for (int k4 = 0; k4 < 16; ++k4) {
        const float* xp = (const float*)&x[k4];
#pragma unroll
        for (int cc = 0; cc < 4; ++cc) {
            int k = k4 * 4 + cc;
            FMA20(as, xp[cc], &Wss[k * MSG]);
            FMA20(ad, xp[cc], &Wds[k * MSG]);
        }
    }

    store_row_h(Ps + (size_t)n * RSTRIDE, as);
    store_row_h(Pd + (size_t)n * RSTRIDE, ad);
}

__device__ __forceinline__ __half2 shflx_h2(__half2 v, int mask) {
    int x; __builtin_memcpy(&x, &v, 4);
    x = __shfl_xor(x, mask, 4);
    __half2 r; __builtin_memcpy(&r, &x, 4);
    return r;
}

// branchless 4-way select by q (0..3): avoids runtime-indexed register arrays
__device__ __forceinline__ __half2 sel4(int q, __half2 a, __half2 b, __half2 c, __half2 d) {
    __half2 ab = (q & 1) ? b : a;
    __half2 cd = (q & 1) ? d : c;
    return (q & 2) ? cd : ab;
}

// Edge kernel v4 ("quad"): 4 lanes per edge, 4 edges per 4-lane group.
// - Reads: lane q reads float4 #(s*4+q) of each row -> every instruction covers
//   full 64B lines (m13 streaming pattern). No LDS staging, no barriers in loop.
// - W (fp16, LDS) read once per k, amortized over 4 edges.
// - Width-4 shfl_xor butterfly -> all lanes hold all 20 sums; sel4 picks the
//   16B quarter each lane writes. Ps gathered as 4x16B coalesced 64B rows.
// - CSR slot via one atomic per lane (its own edge), broadcast with __shfl.
__global__ __launch_bounds__(256, 4) void pe_quad_kernel(
    const int* __restrict__ ei,
    const float* __restrict__ edge_attr,
    const float* __restrict__ W, const float* __restrict__ b,
    const __half* __restrict__ Ps,
    int* __restrict__ cur,
    __half* __restrict__ PeP)
{
    __shared__ __half2 Wh2[64 * WR2];   // 3072 B
    __shared__ __half2 bh[16];

    const int t = threadIdx.x;
    const int q = t & 3;
    const int e0 = blockIdx.x * 256 + (t >> 2) * 4;   // group's first edge (grid exact: 3125*256=800K)

    // stage W_e rows as half2 (k 0..63, 12 half2/row incl pad)
    for (int i = t; i < 64 * WR2; i += 256) {
        int k = i / WR2, j = i - k * WR2;
        __half2 v = __floats2half2_rn(0.0f, 0.0f);
        if (j < 10) v = __floats2half2_rn(W[2 * DF * MSG + k * MSG + 2 * j],
                                          W[2 * DF * MSG + k * MSG + 2 * j + 1]);
        Wh2[i] = v;
    }
    if (t < 16) {
        __half2 v = __floats2half2_rn(0.0f, 0.0f);
        if (t < 10) v = __floats2half2_rn(b[2 * t], b[2 * t + 1]);
        bh[t] = v;
    }

    // per-lane edge for the atomic/gather phase
    const int eq = e0 + q;
    const int srcq = ei[eq];
    const int dstq = ei[EDGES + eq];

    // load this lane's k-quarter of 4 edge rows; convert to half2
    // lane q, chunk s -> float4 #(s*4+q) -> k in [16s+4q, 16s+4q+4)
    const float4* ea4 = (const float4*)edge_attr;
    __half2 xh[4][8];
#pragma unroll
    for (int i = 0; i < 4; ++i) {
        size_t rb = (size_t)(e0 + i) * 16 + q;
        float4 v0 = ea4[rb + 0];
        float4 v1 = ea4[rb + 4];
        float4 v2 = ea4[rb + 8];
        float4 v3 = ea4[rb + 12];
        xh[i][0] = __floats2half2_rn(v0.x, v0.y); xh[i][1] = __floats2half2_rn(v0.z, v0.w);
        xh[i][2] = __floats2half2_rn(v1.x, v1.y); xh[i][3] = __floats2half2_rn(v1.z, v1.w);
        xh[i][4] = __floats2half2_rn(v2.x, v2.y); xh[i][5] = __floats2half2_rn(v2.z, v2.w);
        xh[i][6] = __floats2half2_rn(v3.x, v3.y); xh[i][7] = __floats2half2_rn(v3.z, v3.w);
    }

    __syncthreads();   // Wh2/bh ready

    __half2 acc[4][10];
#pragma unroll
    for (int i = 0; i < 4; ++i)
#pragma unroll
        for (int j = 0; j < 10; ++j) acc[i][j] = __floats2half2_rn(0.0f, 0.0f);

    // compute: 16 k per lane; W row read once per k, used for 4 edges
#pragma unroll
    for (int s = 0; s < 4; ++s) {
#pragma unroll
        for (int d = 0; d < 2; ++d) {
#pragma unroll
            for (int lh = 0; lh < 2; ++lh) {
                int k = s * 16 + q * 4 + 2 * d + lh;
                const __half2* wr = Wh2 + k * WR2;
                __half2 wa[10];
#pragma unroll
                for (int j = 0; j < 10; ++j) wa[j] = wr[j];
#pragma unroll
                for (int i = 0; i < 4; ++i) {
                    __half2 xb = lh ? __high2half2(xh[i][s * 2 + d])
                                    : __low2half2(xh[i][s * 2 + d]);
#pragma unroll
                    for (int j = 0; j < 10; ++j)
                        acc[i][j] = __hfma2(xb, wa[j], acc[i][j]);
                }
            }
        }
    }

    // width-4 butterfly: all 4 lanes get full sums for all 4 edges
#pragma unroll
    for (int i = 0; i < 4; ++i)
#pragma unroll
        for (int j = 0; j < 10; ++j) {
            acc[i][j] = __hadd2(acc[i][j], shflx_h2(acc[i][j], 1));
            acc[i][j] = __hadd2(acc[i][j], shflx_h2(acc[i][j], 2));
        }

    // + bias (after reduce!)
#pragma unroll
    for (int i = 0; i < 4; ++i)
#pragma unroll
        for (int j = 0; j < 10; ++j) acc[i][j] = __hadd2(acc[i][j], bh[j]);

    // CSR slot: each lane atomics for its own edge, then broadcast per i
    int p = atomicAdd(&cur[dstq], 1);

    const __half2 hz = __floats2half2_rn(0.0f, 0.0f);
#pragma unroll
    for (int i = 0; i < 4; ++i) {
        int pi = __shfl(p, i, 4);
        int si = __shfl(srcq, i, 4);

        // lane q's quarter = output pairs q*4+c (c=0..3); pairs >=10 are zero
        __half2 o0 = sel4(q, acc[i][0], acc[i][4], acc[i][8], hz);
        __half2 o1 = sel4(q, acc[i][1], acc[i][5], acc[i][9], hz);
        __half2 o2 = sel4(q, acc[i][2], acc[i][6], hz,        hz);
        __half2 o3 = sel4(q, acc[i][3], acc[i][7], hz,        hz);

        // + Ps[si] quarter (coalesced 64B row gather across the 4 lanes)
        uint4 ps = *(const uint4*)(Ps + (size_t)si * RSTRIDE + q * 8);
        union { uint4 u; __half2 h[4]; } pu; pu.u = ps;
        union { uint4 u; __half2 h[4]; } ou;
        ou.h[0] = __hadd2(o0, pu.h[0]);
        ou.h[1] = __hadd2(o1, pu.h[1]);
        ou.h[2] = __hadd2(o2, pu.h[2]);
        ou.h[3] = __hadd2(o3, pu.h[3]);

        *(uint4*)(PeP + (size_t)pi * RSTRIDE + q * 8) = ou.u;
    }
}

// Node-centric aggregate: 4 lanes per node stream contiguous fp16 CSR rows,
// acc += relu(row + Pd[node]); quad shfl-reduce; 20->20->10 MLP; atomic into gacc.
__global__ __launch_bounds__(256) void agg_kernel(const int* __restrict__ rs,
                                                  const __half* __restrict__ PeP,
                                                  const __half* __restrict__ Pd,
                                                  const float* __restrict__ W1, const float* __restrict__ b1,
                                                  const float* __restrict__ W2, const float* __restrict__ b2,
                                                  const int* __restrict__ batch, float* __restrict__ gacc) {
    __shared__ float W1s[MSG * MSG], W2s[MSG * HID2], b1s[MSG], b2s[HID2];
    for (int i = threadIdx.x; i < MSG * MSG; i += 256) W1s[i] = W1[i];
    for (int i = threadIdx.x; i < MSG * HID2; i += 256) W2s[i] = W2[i];
    if (threadIdx.x < MSG) b1s[threadIdx.x] = b1[threadIdx.x];
    if (threadIdx.x < HID2) b2s[threadIdx.x] = b2[threadIdx.x];
    __syncthreads();

    int t = threadIdx.x;
    int node = blockIdx.x * 64 + (t >> 2);
    int lane = t & 3;

    float acc[MSG];
#pragma unroll
    for (int j = 0; j < MSG; ++j) acc[j] = 0.0f;

    if (node < NODES) {
        int s0 = rs[node];
        int deg = rs[node + 1] - s0;

        float pd[MSG];
        {
            const uint4* pr = (const uint4*)(Pd + (size_t)node * RSTRIDE);
            union { uint4 q; __half2 h2[4]; } a0, a1;
            union { uint2 q; __half2 h2[2]; } a2;
            a0.q = pr[0]; a1.q = pr[1]; a2.q = *(const uint2*)(pr + 2);
#pragma unroll
            for (int i = 0; i < 4; ++i) {
                float2 f = __half22float2(a0.h2[i]);
                pd[2 * i] = f.x; pd[2 * i + 1] = f.y;
            }
#pragma unroll
            for (int i = 0; i < 4; ++i) {
                float2 f = __half22float2(a1.h2[i]);
                pd[8 + 2 * i] = f.x; pd[9 + 2 * i] = f.y;
            }
#pragma unroll
            for (int i = 0; i < 2; ++i) {
                float2 f = __half22float2(a2.h2[i]);
                pd[16 + 2 * i] = f.x; pd[17 + 2 * i] = f.y;
            }
        }

        for (int i = lane; i < deg; i += 4) {
            const uint4* rp = (const uint4*)(PeP + (size_t)(s0 + i) * RSTRIDE);
            uint4 q0 = rp[0], q1 = rp[1];
            uint2 q2 = *(const uint2*)(rp + 2);
            union { uint4 q; __half2 h2[4]; } a0, a1;
            union { uint2 q; __half2 h2[2]; } a2;
            a0.q = q0; a1.q = q1; a2.q = q2;
#pragma unroll
            for (int k = 0; k < 4; ++k) {
                float2 f = __half22float2(a0.h2[k]);
                acc[2 * k]     += fmaxf(f.x + pd[2 * k], 0.0f);
                acc[2 * k + 1] += fmaxf(f.y + pd[2 * k + 1], 0.0f);
            }
#pragma unroll
            for (int k = 0; k < 4; ++k) {
                float2 f = __half22float2(a1.h2[k]);
                acc[8 + 2 * k] += fmaxf(f.x + pd[8 + 2 * k], 0.0f);
                acc[9 + 2 * k] += fmaxf(f.y + pd[9 + 2 * k], 0.0f);
            }
#pragma unroll
            for (int k = 0; k < 2; ++k) {
                float2 f = __half22float2(a2.h2[k]);
                acc[16 + 2 * k] += fmaxf(f.x + pd[16 + 2 * k], 0.0f);
                acc[17 + 2 * k] += fmaxf(f.y + pd[17 + 2 * k], 0.0f);
            }
        }
    }

#pragma unroll
    for (int j = 0; j < MSG; ++j) acc[j] += __shfl_xor(acc[j], 1);
#pragma unroll
    for (int j = 0; j < MSG; ++j) acc[j] += __shfl_xor(acc[j], 2);

    if (node < NODES && lane == 0) {
        float t1[MSG];
#pragma unroll
        for (int j = 0; j < MSG; ++j) t1[j] = b1s[j];
#pragma unroll
        for (int k = 0; k < MSG; ++k)
#pragma unroll
            for (int j = 0; j < MSG; ++j) t1[j] = fmaf(acc[k], W1s[k * MSG + j], t1[j]);
#pragma unroll
        for (int j = 0; j < MSG; ++j) t1[j] = fmaxf(t1[j], 0.0f);

        float t2[HID2];
#pragma unroll
        for (int m = 0; m < HID2; ++m) t2[m] = b2s[m];
#pragma unroll
        for (int k = 0; k < MSG; ++k)
#pragma unroll
            for (int m = 0; m < HID2; ++m) t2[m] = fmaf(t1[k], W2s[k * HID2 + m], t2[m]);

        int g = batch[node];
        float* gr = gacc + (size_t)g * HID2;
#pragma unroll
        for (int m = 0; m < HID2; ++m) atomicAdd(gr + m, fmaxf(t2[m], 0.0f));
    }
}

__global__ void graph_kernel(const float* __restrict__ gacc,
                             const float* __restrict__ W3, const float* __restrict__ b3,
                             const float* __restrict__ W4, const float* __restrict__ b4,
                             float* __restrict__ out) {
    int g = blockIdx.x * blockDim.x + threadIdx.x;
    if (g >= GRAPHS) return;

    float h[HID2];
#pragma unroll
    for (int m = 0; m < HID2; ++m) h[m] = gacc[(size_t)g * HID2 + m];

    float t[HID2];
#pragma unroll
    for (int j = 0; j < HID2; ++j) {
        float s = b3[j];
#pragma unroll
        for (int k = 0; k < HID2; ++k) s = fmaf(h[k], W3[k * HID2 + j], s);
        t[j] = fmaxf(s, 0.0f);
    }
    float s = b4[0];
#pragma unroll
    for (int k = 0; k < HID2; ++k) s = fmaf(t[k], W4[k], s);
    out[g] = s;
}

extern "C" void kernel_launch(void* const* d_in, const int* in_sizes, int n_in,
                              void* d_out, int out_size, void* d_ws, size_t ws_size,
                              hipStream_t stream) {
    const int*   ei        = (const int*)  d_in[0];
    const float* node_attr = (const float*)d_in[1];
    const float* edge_attr = (const float*)d_in[2];
    const int*   batch     = (const int*)  d_in[3];
    const float* W_mpl     = (const float*)d_in[4];
    const float* b_mpl     = (const float*)d_in[5];
    const float* W1        = (const float*)d_in[6];
    const float* b1        = (const float*)d_in[7];
    const float* W2        = (const float*)d_in[8];
    const float* b2        = (const float*)d_in[9];
    const float* W3        = (const float*)d_in[10];
    const float* b3        = (const float*)d_in[11];
    const float* W4        = (const float*)d_in[12];
    const float* b4        = (const float*)d_in[13];
    float* out = (float*)d_out;

    // workspace layout (all offsets multiples of 64B)
    __half* PeP = (__half*)d_ws;                          // E*32 halves (51.2 MB), CSR-ordered
    __half* Ps  = PeP + (size_t)EDGES * RSTRIDE;          // N*32 halves (3.2 MB)
    __half* Pd  = Ps + (size_t)NODES * RSTRIDE;           // N*32 halves (3.2 MB)
    float* gacc = (float*)(Pd + (size_t)NODES * RSTRIDE); // G*10
    int* cnt    = (int*)(gacc + GRAPHS * HID2);           // N (padded 50176)
    int* rs     = cnt + 50176;                            // N+1 (padded)
    int* cur    = rs + 50176;                             // N (padded)
    int* bsum   = cur + 50176;                            // 256
    int* bscan  = bsum + 256;                             // 256

    int egrid  = (EDGES + 255) / 256;   // 3125
    int ngrid  = NB1;                   // 196

    hipLaunchKernelGGL(zero2_kernel, dim3(256), dim3(256), 0, stream, cnt, gacc);
    hipLaunchKernelGGL(count_kernel, dim3(egrid), dim3(256), 0, stream, ei, cnt);
    hipLaunchKernelGGL(scan_block, dim3(ngrid), dim3(256), 0, stream, cnt, rs, bsum, NODES);
    hipLaunchKernelGGL(scan_block, dim3(1), dim3(256), 0, stream, bsum, bscan, (int*)nullptr, NB1);
    hipLaunchKernelGGL(fixup_pn_kernel, dim3(ngrid), dim3(256), 0, stream,
                       rs, cur, bscan, node_attr, W_mpl, Ps, Pd);
    hipLaunchKernelGGL(pe_quad_kernel, dim3(egrid), dim3(256), 0, stream,
                       ei, edge_attr, W_mpl, b_mpl, Ps, cur, PeP);
    hipLaunchKernelGGL(agg_kernel, dim3((NODES + 63) / 64), dim3(256), 0, stream,
                       rs, PeP, Pd, W1, b1, W2, b2, batch, gacc);
    hipLaunchKernelGGL(graph_kernel, dim3(2), dim3(256), 0, stream, gacc, W3, b3, W4, b4, out);
}